// Round 11
// baseline (339.054 us; speedup 1.0000x reference)
//
#include <hip/hip_runtime.h>
#include <hip/hip_bf16.h>

#define CL 2
#define CB 4
#define CT 1024
#define CD 256
#define CH 4
#define CM 1024
#define CHD (CH * CD)      // 1024
#define NROW (CB * CT)     // 4096

typedef unsigned short ushort_t;
typedef __attribute__((ext_vector_type(8))) short short8v;   // 8 bf16 (4 VGPR)
typedef __attribute__((ext_vector_type(4))) float float4v;   // MFMA C/D frag

#define LOG2E 1.44269504088896f

__device__ __forceinline__ float bf2f(unsigned short u) {
    return __uint_as_float(((unsigned int)u) << 16);
}
__device__ __forceinline__ unsigned short f2bf(float f) {
    unsigned int x = __float_as_uint(f);
    return (unsigned short)((x + 0x7fffu + ((x >> 16) & 1u)) >> 16);
}

// ---------------------------------------------------------------------------
// Input-dtype detection (2048 elems; fp32-underlying -> ~430 anomalies, bf16 0)
// ---------------------------------------------------------------------------
__global__ __launch_bounds__(256) void detect_kernel(
    const ushort_t* __restrict__ w, int n, int* __restrict__ flag)
{
    __shared__ int red[256];
    int c = 0;
    for (int i = threadIdx.x; i < n; i += 256) {
        float v = bf2f(w[i]);
        if (!(fabsf(v) <= 1e6f)) c++;
    }
    red[threadIdx.x] = c;
    __syncthreads();
    for (int s = 128; s > 0; s >>= 1) {
        if (threadIdx.x < s) red[threadIdx.x] += red[threadIdx.x + s];
        __syncthreads();
    }
    if (threadIdx.x == 0) flag[0] = (red[0] < 8) ? 1 : 0;
}

// ---------------------------------------------------------------------------
// Prepass transpose: Wq/Wk/Wv/W1 (all [L][256][1024]) -> bf16 transposed.
// Grid (32, 8, 8): z = which*2 + l.
// ---------------------------------------------------------------------------
__global__ __launch_bounds__(256) void tconv_all(
    const void* __restrict__ Wq, const void* __restrict__ Wk,
    const void* __restrict__ Wv, const void* __restrict__ W1,
    ushort_t* __restrict__ wqkvT, ushort_t* __restrict__ w1T,
    const int* __restrict__ flagp)
{
    const int fbf = *flagp;
    const int z = blockIdx.z;
    const int which = z >> 1, l = z & 1;
    const void* in = (which == 0) ? Wq : (which == 1) ? Wk
                   : (which == 2) ? Wv : W1;
    ushort_t* out = (which < 3)
        ? wqkvT + (long)l * 3072 * 256 + (long)which * 1024 * 256
        : w1T + (long)l * 1024 * 256;
    const long zi = (long)l * 262144;

    __shared__ float tile[32][33];
    const int r0 = blockIdx.y * 32;
    const int c0 = blockIdx.x * 32;
    const int tx = threadIdx.x & 31;
    const int ty = threadIdx.x >> 5;
#pragma unroll
    for (int i = 0; i < 32; i += 8) {
        const long idx = zi + (long)(r0 + ty + i) * 1024 + c0 + tx;
        tile[ty + i][tx] = fbf ? bf2f(((const ushort_t*)in)[idx])
                               : ((const float*)in)[idx];
    }
    __syncthreads();
#pragma unroll
    for (int i = 0; i < 32; i += 8)
        out[(long)(c0 + ty + i) * 256 + r0 + tx] = f2bf(tile[tx][ty + i]);
}

// ---------------------------------------------------------------------------
// In-loop transpose: Wo & W2 (both [L][1024][256]) -> wscr[z][256][1024].
// ---------------------------------------------------------------------------
__global__ __launch_bounds__(256) void tconv2(
    const void* __restrict__ Wo, const void* __restrict__ W2,
    ushort_t* __restrict__ wscr, long ioff, const int* __restrict__ flagp)
{
    const int fbf = *flagp;
    const int z = blockIdx.z;
    const void* in = z ? W2 : Wo;
    ushort_t* out = wscr + (long)z * 262144;

    __shared__ float tile[32][33];
    const int r0 = blockIdx.y * 32;
    const int c0 = blockIdx.x * 32;
    const int tx = threadIdx.x & 31;
    const int ty = threadIdx.x >> 5;
#pragma unroll
    for (int i = 0; i < 32; i += 8) {
        const long idx = ioff + (long)(r0 + ty + i) * 256 + c0 + tx;
        tile[ty + i][tx] = fbf ? bf2f(((const ushort_t*)in)[idx])
                               : ((const float*)in)[idx];
    }
    __syncthreads();
#pragma unroll
    for (int i = 0; i < 32; i += 8)
        out[(long)(c0 + ty + i) * 1024 + r0 + tx] = f2bf(tile[tx][ty + i]);
}

// ---------------------------------------------------------------------------
// QKV projection (merged, verified r7-r10; LDS rows padded to 40 ushorts
// this round to break the stride-32 bank aliasing).
// ---------------------------------------------------------------------------
__global__ __launch_bounds__(256) void qkv_proj(
    const ushort_t* __restrict__ A, const ushort_t* __restrict__ B,
    const void* __restrict__ bq, const void* __restrict__ bk,
    const void* __restrict__ bv, ushort_t* __restrict__ qk,
    ushort_t* __restrict__ vT, long boff, const int* __restrict__ flagp)
{
    const long m0 = (long)blockIdx.y * 128;
    const long n0 = (long)blockIdx.x * 128;

    __shared__ __align__(16) ushort_t As[128 * 40];
    __shared__ __align__(16) ushort_t Bs[128 * 40];

    const int tid = threadIdx.x;
    const int wave = tid >> 6;
    const int lane = tid & 63;
    const int quad = lane >> 4;
    const int lrow = lane & 15;
    const int wm = (wave >> 1) * 64;
    const int wn = (wave & 1) * 64;

    float4v acc[4][4];
#pragma unroll
    for (int i = 0; i < 4; ++i)
#pragma unroll
        for (int j = 0; j < 4; ++j)
            acc[i][j] = (float4v){0.f, 0.f, 0.f, 0.f};

    for (int k0 = 0; k0 < 256; k0 += 32) {
        __syncthreads();
#pragma unroll
        for (int p = 0; p < 2; ++p) {
            const int c = p * 256 + tid;
            const int row = c >> 2;
            const int kk = (c & 3) << 3;
            *reinterpret_cast<short8v*>(&As[row * 40 + kk]) =
                *reinterpret_cast<const short8v*>(&A[(m0 + row) * 256 + k0 + kk]);
            *reinterpret_cast<short8v*>(&Bs[row * 40 + kk]) =
                *reinterpret_cast<const short8v*>(&B[(n0 + row) * 256 + k0 + kk]);
        }
        __syncthreads();

        short8v af[4], bfv[4];
#pragma unroll
        for (int i = 0; i < 4; ++i) {
            af[i]  = *reinterpret_cast<const short8v*>(&As[(wm + i * 16 + lrow) * 40 + quad * 8]);
            bfv[i] = *reinterpret_cast<const short8v*>(&Bs[(wn + i * 16 + lrow) * 40 + quad * 8]);
        }
#pragma unroll
        for (int mi = 0; mi < 4; ++mi)
#pragma unroll
            for (int ni = 0; ni < 4; ++ni)
                acc[mi][ni] = __builtin_amdgcn_mfma_f32_16x16x32_bf16(
                    af[mi], bfv[ni], acc[mi][ni], 0, 0, 0);
    }

    const int fbf = *flagp;
#pragma unroll
    for (int mi = 0; mi < 4; ++mi) {
#pragma unroll
        for (int ni = 0; ni < 4; ++ni) {
            const long col = n0 + wn + ni * 16 + lrow;
            const long row0 = m0 + wm + mi * 16 + quad * 4;
            const void* bp;
            long bn;
            if (col < 1024)      { bp = bq; bn = col; }
            else if (col < 2048) { bp = bk; bn = col - 1024; }
            else                 { bp = bv; bn = col - 2048; }
            const float bias = fbf ? bf2f(((const ushort_t*)bp)[boff + bn])
                                   : ((const float*)bp)[boff + bn];
            if (col < 2048) {
#pragma unroll
                for (int r = 0; r < 4; ++r)
                    qk[(row0 + r) * 2048 + col] = f2bf(acc[mi][ni][r] + bias);
            } else {
                const long d = col - 2048;
                const long addr = ((row0 >> 10) << 2) * 262144 + d * 1024 + (row0 & 1023);
                ushort4 u;
                u.x = f2bf(acc[mi][ni][0] + bias);
                u.y = f2bf(acc[mi][ni][1] + bias);
                u.z = f2bf(acc[mi][ni][2] + bias);
                u.w = f2bf(acc[mi][ni][3] + bias);
                *reinterpret_cast<ushort4*>(&vT[addr]) = u;
            }
        }
    }
}

// ---------------------------------------------------------------------------
// mgemm64b: 64x64-tile full-K GEMM (MLP1), bias+relu, bf16 out. Padded LDS.
// ---------------------------------------------------------------------------
template <int RELU>
__global__ __launch_bounds__(256) void mgemm64b(
    const ushort_t* __restrict__ A, const ushort_t* __restrict__ B,
    const void* __restrict__ bias, ushort_t* __restrict__ C,
    int K, int lda, int ldb, int ldc, long boff,
    const int* __restrict__ flagp)
{
    const long m0 = (long)blockIdx.y * 64;
    const long n0 = (long)blockIdx.x * 64;

    __shared__ __align__(16) ushort_t As[64 * 40];
    __shared__ __align__(16) ushort_t Bs[64 * 40];

    const int tid = threadIdx.x;
    const int wave = tid >> 6;
    const int lane = tid & 63;
    const int quad = lane >> 4;
    const int lrow = lane & 15;
    const int wm = (wave >> 1) * 32;
    const int wn = (wave & 1) * 32;

    const int ar = tid >> 2;
    const int ak = (tid & 3) << 3;

    float4v acc[2][2];
#pragma unroll
    for (int i = 0; i < 2; ++i)
#pragma unroll
        for (int j = 0; j < 2; ++j)
            acc[i][j] = (float4v){0.f, 0.f, 0.f, 0.f};

    for (int k0 = 0; k0 < K; k0 += 32) {
        __syncthreads();
        *reinterpret_cast<short8v*>(&As[ar * 40 + ak]) =
            *reinterpret_cast<const short8v*>(&A[(m0 + ar) * (long)lda + k0 + ak]);
        *reinterpret_cast<short8v*>(&Bs[ar * 40 + ak]) =
            *reinterpret_cast<const short8v*>(&B[(n0 + ar) * (long)ldb + k0 + ak]);
        __syncthreads();

        short8v af[2], bfv[2];
#pragma unroll
        for (int i = 0; i < 2; ++i) {
            af[i]  = *reinterpret_cast<const short8v*>(&As[(wm + i * 16 + lrow) * 40 + quad * 8]);
            bfv[i] = *reinterpret_cast<const short8v*>(&Bs[(wn + i * 16 + lrow) * 40 + quad * 8]);
        }
#pragma unroll
        for (int mi = 0; mi < 2; ++mi)
#pragma unroll
            for (int ni = 0; ni < 2; ++ni)
                acc[mi][ni] = __builtin_amdgcn_mfma_f32_16x16x32_bf16(
                    af[mi], bfv[ni], acc[mi][ni], 0, 0, 0);
    }

    const int fbf = *flagp;
#pragma unroll
    for (int mi = 0; mi < 2; ++mi)
#pragma unroll
        for (int ni = 0; ni < 2; ++ni) {
            const long col = n0 + wn + ni * 16 + lrow;
            const long row0 = m0 + wm + mi * 16 + quad * 4;
            const float bv = fbf ? bf2f(((const ushort_t*)bias)[boff + col])
                                 : ((const float*)bias)[boff + col];
#pragma unroll
            for (int r = 0; r < 4; ++r) {
                float v = acc[mi][ni][r] + bv;
                if (RELU) v = fmaxf(v, 0.f);
                C[(row0 + r) * (long)ldc + col] = f2bf(v);
            }
        }
}

// ---------------------------------------------------------------------------
// gemm_ln: fused (O-proj | MLP2) + bias + residual + LayerNorm.
// Replaces mgemm64s + pgem round-trip + ln_p (r10: that chain was ~20 us and
// 2 launch gaps per pair). Full K=1024 (NO split-K, no cross-block comms ->
// XCD-safe). Tile 16 rows x 256 cols (full N -> LN is in-block). Grid 256.
// Wave w owns cols w*64..w*64+63 (4 n-tiles). A: AMODE 0 = plain bf16 [M][1024];
// AMODE 1 = attention partials op0/op1 combined via per-(row,h) scales
// precomputed into LDS once per block. FINAL=1 writes d_out in flag dtype.
// ---------------------------------------------------------------------------
template <int AMODE, int FINAL>
__global__ __launch_bounds__(256) void gemm_ln(
    const ushort_t* __restrict__ A, const ushort_t* __restrict__ Ap1,
    const float2* __restrict__ ml, const ushort_t* __restrict__ B,
    const void* __restrict__ gb, long goff,
    const ushort_t* __restrict__ res, const void* __restrict__ sc,
    const void* __restrict__ bi, void* __restrict__ out, long loff,
    const int* __restrict__ flagp)
{
    const long m0 = (long)blockIdx.x * 16;

    __shared__ __align__(16) ushort_t As[16 * 40];
    __shared__ __align__(16) ushort_t Bs[256 * 40];
    __shared__ float mlc[16][4][2];
    __shared__ float red1[4][16];
    __shared__ float red2[4][16];
    __shared__ float stat[2][16];

    const int tid = threadIdx.x;
    const int wave = tid >> 6;
    const int lane = tid & 63;
    const int quad = lane >> 4;
    const int lrow = lane & 15;

    if constexpr (AMODE == 1) {
        if (tid < 64) {
            const int r = tid >> 2, hh = tid & 3;
            const long m = m0 + r;
            const int bh = ((int)(m >> 10) << 2) + hh;
            const int trow = (int)(m & 1023);
            const float2 v0 = ml[bh * 1024 + trow];
            const float2 v1 = ml[(16 + bh) * 1024 + trow];
            const float mm = fmaxf(v0.x, v1.x);
            const float a0 = exp2f(v0.x - mm);
            const float a1 = exp2f(v1.x - mm);
            const float inv = 1.0f / (v0.y * a0 + v1.y * a1);
            mlc[r][hh][0] = a0 * inv;
            mlc[r][hh][1] = a1 * inv;
        }
    }

    float4v acc[4];
#pragma unroll
    for (int i = 0; i < 4; ++i) acc[i] = (float4v){0.f, 0.f, 0.f, 0.f};

    for (int k0 = 0; k0 < 1024; k0 += 32) {
        __syncthreads();
        // stage A 16x32
        {
            const int row = tid >> 4;
            const int c2 = (tid & 15) << 1;
            const long ga = (m0 + row) * 1024 + k0 + c2;
            if constexpr (AMODE == 0) {
                *reinterpret_cast<ushort2*>(&As[row * 40 + c2]) =
                    *reinterpret_cast<const ushort2*>(&A[ga]);
            } else {
                const int hh = k0 >> 8;
                const float s0 = mlc[row][hh][0];
                const float s1 = mlc[row][hh][1];
                const ushort2 p0 = *reinterpret_cast<const ushort2*>(&A[ga]);
                const ushort2 p1 = *reinterpret_cast<const ushort2*>(&Ap1[ga]);
                ushort2 o;
                o.x = f2bf(bf2f(p0.x) * s0 + bf2f(p1.x) * s1);
                o.y = f2bf(bf2f(p0.y) * s0 + bf2f(p1.y) * s1);
                *reinterpret_cast<ushort2*>(&As[row * 40 + c2]) = o;
            }
        }
        // stage B 256x32
#pragma unroll
        for (int p = 0; p < 4; ++p) {
            const int c = p * 256 + tid;
            const int n = c >> 2, kc = (c & 3) << 3;
            *reinterpret_cast<short8v*>(&Bs[n * 40 + kc]) =
                *reinterpret_cast<const short8v*>(&B[(long)n * 1024 + k0 + kc]);
        }
        __syncthreads();

        short8v af = *reinterpret_cast<const short8v*>(&As[lrow * 40 + quad * 8]);
#pragma unroll
        for (int ni = 0; ni < 4; ++ni) {
            short8v bfv = *reinterpret_cast<const short8v*>(
                &Bs[(wave * 64 + ni * 16 + lrow) * 40 + quad * 8]);
            acc[ni] = __builtin_amdgcn_mfma_f32_16x16x32_bf16(af, bfv, acc[ni], 0, 0, 0);
        }
    }

    // epilogue: x = acc + bias + residual; LN over 256 cols per row
    const int fbf = *flagp;
    float x[4][4];   // [ni][r]; row = quad*4+r, col = wave*64+ni*16+lrow
    float s1[4] = {0.f, 0.f, 0.f, 0.f}, s2[4] = {0.f, 0.f, 0.f, 0.f};
#pragma unroll
    for (int ni = 0; ni < 4; ++ni) {
        const int col = wave * 64 + ni * 16 + lrow;
        const float gbv = fbf ? bf2f(((const ushort_t*)gb)[goff + col])
                              : ((const float*)gb)[goff + col];
#pragma unroll
        for (int r = 0; r < 4; ++r) {
            const long row = m0 + quad * 4 + r;
            const float v = acc[ni][r] + gbv + bf2f(res[row * 256 + col]);
            x[ni][r] = v;
            s1[r] += v;
            s2[r] += v * v;
        }
    }
#pragma unroll
    for (int r = 0; r < 4; ++r) {
#pragma unroll
        for (int sh = 1; sh < 16; sh <<= 1) {
            s1[r] += __shfl_xor(s1[r], sh);
            s2[r] += __shfl_xor(s2[r], sh);
        }
    }
    if (lrow == 0) {
#pragma unroll
        for (int r = 0; r < 4; ++r) {
            red1[wave][quad * 4 + r] = s1[r];
            red2[wave][quad * 4 + r] = s2[r];
        }
    }
    __syncthreads();
    if (tid < 16) {
        const float t1 = red1[0][tid] + red1[1][tid] + red1[2][tid] + red1[3][tid];
        const float t2 = red2[0][tid] + red2[1][tid] + red2[2][tid] + red2[3][tid];
        const float mean = t1 * (1.0f / 256.0f);
        const float var = t2 * (1.0f / 256.0f) - mean * mean;
        stat[0][tid] = mean;
        stat[1][tid] = rsqrtf(var + 1e-5f);
    }
    __syncthreads();

#pragma unroll
    for (int ni = 0; ni < 4; ++ni) {
        const int col = wave * 64 + ni * 16 + lrow;
        const float scv = fbf ? bf2f(((const ushort_t*)sc)[loff + col])
                              : ((const float*)sc)[loff + col];
        const float biv = fbf ? bf2f(((const ushort_t*)bi)[loff + col])
                              : ((const float*)bi)[loff + col];
#pragma unroll
        for (int r = 0; r < 4; ++r) {
            const int rr = quad * 4 + r;
            const float y = (x[ni][r] - stat[0][rr]) * stat[1][rr] * scv + biv;
            const long oidx = (m0 + rr) * 256 + col;
            if constexpr (FINAL) {
                if (fbf) ((ushort_t*)out)[oidx] = f2bf(y);
                else     ((float*)out)[oidx] = y;
            } else {
                ((ushort_t*)out)[oidx] = f2bf(y);
            }
        }
    }
}

// ---------------------------------------------------------------------------
// Flash attention v6 = r10's proven structure (32-key tiles, K+V LDS, S^T
// softmax) + (a) LAZY rescale: softmax reference updates only when the tile
// max exceeds it by >1.0 in log2 (P bounded by 2.0 — harmless; skips the
// 64-mul oacc rescale + alpha exp most iterations), (b) packed Ps stores
// (2 x b64 instead of 8 x u16).
// ---------------------------------------------------------------------------
__global__ __launch_bounds__(256) void flash_attn(
    const ushort_t* __restrict__ qk, const ushort_t* __restrict__ vT,
    ushort_t* __restrict__ op0, ushort_t* __restrict__ op1,
    float2* __restrict__ ml)
{
    const int bx = blockIdx.x;
    const int bh = bx & 15;
    const int qt = (bx >> 4) & 15;
    const int ck = bx >> 8;
    const int b = bh >> 2, h = bh & 3;

    __shared__ __align__(16) ushort_t Ks[32 * 264];
    __shared__ __align__(16) ushort_t Vs[256 * 40];
    __shared__ __align__(16) ushort_t Ps[4][16 * 40];

    const int tid = threadIdx.x;
    const int wave = tid >> 6;
    const int lane = tid & 63;
    const int quad = lane >> 4;
    const int lrow = lane & 15;

    const long qrow0 = (long)b * CT + qt * 64;
    const int qcol = h * 256;
    const int kcol = 1024 + h * 256;
    const long vbase = (long)bh * 256 * 1024;
    const float SC = 0.0625f * LOG2E;

    short8v qf[8];
#pragma unroll
    for (int kk = 0; kk < 8; ++kk)
        qf[kk] = *reinterpret_cast<const short8v*>(
            &qk[(qrow0 + wave * 16 + lrow) * 2048 + qcol + kk * 32 + quad * 8]);

    float mrun = -1e30f, lrun = 0.f;
    float4v oacc[16];
#pragma unroll
    for (int i = 0; i < 16; ++i) oacc[i] = (float4v){0.f, 0.f, 0.f, 0.f};

    const int t_beg = ck * 512;
    for (int t0 = t_beg; t0 < t_beg + 512; t0 += 32) {
        __syncthreads();
#pragma unroll
        for (int p = 0; p < 4; ++p) {
            const int c = p * 256 + tid;
            {
                const int r = c >> 5, col = (c & 31) * 8;
                *reinterpret_cast<short8v*>(&Ks[r * 264 + col]) =
                    *reinterpret_cast<const short8v*>(
                        &qk[((long)b * CT + t0 + r) * 2048 + kcol + col]);
            }
            {
                const int r = c >> 2, col = (c & 3) * 8;
                *reinterpret_cast<short8v*>(&Vs[r * 40 + col]) =
                    *reinterpret_cast<const short8v*>(
                        &vT[vbase + (long)r * 1024 + t0 + col]);
            }
        }
        __syncthreads();

        float4v sacc[2];
        sacc[0] = (float4v){0.f, 0.f, 0.f, 0.f};
        sacc[1] = (float4v){0.f, 0.f, 0.f, 0.f};
#pragma unroll
        for (int kk = 0; kk < 8; ++kk) {
#pragma unroll
            for (int ni = 0; ni < 2; ++ni) {
                short8v bk = *reinterpret_cast<const short8v*>(
                    &Ks[(ni * 16 + lrow) * 264 + kk * 32 + quad * 8]);
                sacc[ni] = __builtin_amdgcn_mfma_f32_16x16x32_bf16(
                    bk, qf[kk], sacc[ni], 0, 0, 0);   // swapped -> S^T
            }
        }
#pragma unroll
        for (int ni = 0; ni < 2; ++ni)
#pragma unroll
            for (int r = 0; r < 4; ++r)
                sacc[ni][r] *= SC;

        // tile max for my q-row (lrow), reduced across the quad-duplicates
        float mx = fmaxf(fmaxf(fmaxf(sacc[0][0], sacc[0][1]),
                               fmaxf(sacc[0][2], sacc[0][3])),
                         fmaxf(fmaxf(sacc[1][0], sacc[1][1]),
                               fmaxf(sacc[1][2], sacc[1][3])));
        mx = fmaxf(mx, __shfl_xor(mx, 16));
        mx = fmaxf(mx, __shfl_xor(mx, 32));

        // lazy reference update: only when max moved by >1.0 (log2 domain)
        if (__ballot(mx > mrun + 1.0f) != 0ull) {
            const float mnew = fmaxf(mrun, mx);
            const float alpha = exp2f(mrun - mnew);
            mrun = mnew;
            lrun *= alpha;
            float a4[4];
#pragma unroll
            for (int r = 0; r < 4; ++r)
                a4[r] = __shfl(alpha, quad * 4 + r);
#pragma unroll
            for (int ni = 0; ni < 16; ++ni)
#pragma unroll
                for (int r = 0; r < 4; ++r)
                    oacc[ni][r] *= a4[r];
        }

        float s = 0.f;
#pragma unroll
        for (int ni = 0; ni < 2; ++ni) {
            ushort4 pu;
#pragma unroll
            for (int r = 0; r < 4; ++r) {
                const float pv = exp2f(sacc[ni][r] - mrun);
                s += pv;
                (&pu.x)[r] = f2bf(pv);
            }
            *reinterpret_cast<ushort4*>(
                &Ps[wave][lrow * 40 + ni * 16 + quad * 4]) = pu;
        }
        s += __shfl_xor(s, 16);
        s += __shfl_xor(s, 32);
        lrun += s;

        {
            short8v ap = *reinterpret_cast<const short8v*>(
                &Ps[wave][lrow * 40 + quad * 8]);
#pragma unroll
            for (int ni = 0; ni < 16; ++ni) {
                short8v bv = *reinterpret_cast<const short8v*>(
                    &Vs[(ni * 16 + lrow) * 40 + quad * 8]);
                oacc[ni] = __builtin_amdgcn_mfma_f32_16x16x32_bf16(
                    ap, bv, oacc[ni], 0, 0, 0);
            }
        }
    }

    if (quad == 0)
        ml[((ck << 4) + bh) * 1024 + qt * 64 + wave * 16 + lrow] =
            make_float2(mrun, lrun);

    ushort_t* op = ck ? op1 : op0;
#pragma unroll
    for (int ni = 0; ni < 16; ++ni)
#pragma unroll
        for (int r = 0; r < 4; ++r)
            op[(qrow0 + wave * 16 + quad * 4 + r) * 1024 + (h << 8) + ni * 16 + lrow]
                = f2bf(oacc[ni][r]);
}

__global__ __launch_bounds__(256) void in_convert(
    const void* __restrict__ in, ushort_t* __restrict__ x,
    const int* __restrict__ flagp)
{
    const int fbf = *flagp;
    const long i = ((long)blockIdx.x * 256 + threadIdx.x) << 2;
    if (fbf) {
        *reinterpret_cast<ushort4*>(x + i) =
            *reinterpret_cast<const ushort4*>((const ushort_t*)in + i);
    } else {
        float4 f = *reinterpret_cast<const float4*>((const float*)in + i);
        ushort4 u;
        u.x = f2bf(f.x); u.y = f2bf(f.y); u.z = f2bf(f.z); u.w = f2bf(f.w);
        *reinterpret_cast<ushort4*>(x + i) = u;
    }
}

// ---------------------------------------------------------------------------
// Orchestration. ws = 47.25 MB + 256 B. Dispatches: 3 + 6/layer x 2 = 15.
// ---------------------------------------------------------------------------
extern "C" void kernel_launch(void* const* d_in, const int* in_sizes, int n_in,
                              void* d_out, int out_size, void* d_ws, size_t ws_size,
                              hipStream_t stream)
{
    const void* queries = d_in[0];
    const void* Wq = d_in[1];  const void* bq = d_in[2];
    const void* Wk = d_in[3];  const void* bk = d_in[4];
    const void* Wv = d_in[5];  const void* bv = d_in[6];
    const void* Wo = d_in[7];  const void* bo = d_in[8];
    const void* ln1s = d_in[9];  const void* ln1b = d_in[10];
    const void* W1 = d_in[11]; const void* b1 = d_in[12];
    const void* W2 = d_in[13]; const void* b2 = d_in[14];
    const void* ln2s = d_in[15]; const void* ln2b = d_in[16];

    char* p = (char*)d_ws;
    int* flagp = (int*)p;             p += 256;
    ushort_t* wqkvT = (ushort_t*)p;   p += (long)CL * 3072 * 256 * 2;  // 3 MB
    ushort_t* w1T   = (ushort_t*)p;   p += (long)CL * 1024 * 256 * 2;  // 1 MB
    ushort_t* wscr  = (ushort_t*)p;   p += (long)2 * 256 * 1024 * 2;   // 1 MB
    ushort_t* xa    = (ushort_t*)p;   p += (long)NROW * CD * 2;        // 2 MB
    ushort_t* qk    = (ushort_t*)p;   p += (long)NROW * 2048 * 2;      // 16 MB
    ushort_t* vT    = (ushort_t*)p;   p += (long)16 * 256 * 1024 * 2;  // 8 MB
    ushort_t* op0   = (ushort_t*)p;   p += (long)NROW * 1024 * 2;      // 8 MB
    ushort_t* op1   = (ushort_t*)p;   p += (long)NROW * 1024 * 2;      // 8 MB
    float2*   ml    = (float2*)p;     p += (long)2 * 16 * 1024 * 8;    // 0.25 MB
    ushort_t* h     = vT;             // MLP hidden reuses vT

    detect_kernel<<<1, 256, 0, stream>>>((const ushort_t*)Wq, 2048, flagp);
    tconv_all<<<dim3(32, 8, 8), 256, 0, stream>>>(
        Wq, Wk, Wv, W1, wqkvT, w1T, flagp);
    in_convert<<<(NROW * CD) / 1024, 256, 0, stream>>>(queries, xa, flagp);

    for (int l = 0; l < CL; ++l) {
        // 1) merged QKV projection -> qk [4096,2048] + vT[bh][d][t]
        qkv_proj<<<dim3(24, 32, 1), 256, 0, stream>>>(
            xa, wqkvT + (long)l * 3072 * 256, bq, bk, bv, qk, vT,
            (long)l * 1024, flagp);
        // 2) Wo^T and W2^T in one dispatch -> wscr[0], wscr[1]
        tconv2<<<dim3(8, 32, 2), 256, 0, stream>>>(
            Wo, W2, wscr, (long)l * 1024 * 256, flagp);
        // 3) flash attention (512 blocks, lazy rescale)
        flash_attn<<<512, 256, 0, stream>>>(qk, vT, op0, op1, ml);
        // 4) O-proj + combine + bias + residual + LN1 -> xa  (fused)
        gemm_ln<1, 0><<<256, 256, 0, stream>>>(
            op0, op1, ml, wscr, bo, (long)l * 256, xa, ln1s, ln1b, xa,
            (long)l * 256, flagp);
        // 5) h = relu(xa @ w1T^T + b1)
        mgemm64b<1><<<dim3(16, 64, 1), 256, 0, stream>>>(
            xa, w1T + (long)l * 1024 * 256, b1, h,
            256, 256, 256, 1024, (long)l * 1024, flagp);
        // 6) MLP2 + bias + residual + LN2 -> xa (or d_out on last layer)
        if (l == CL - 1)
            gemm_ln<0, 1><<<256, 256, 0, stream>>>(
                h, nullptr, nullptr, wscr + 262144, b2, (long)l * 256, xa,
                ln2s, ln2b, d_out, (long)l * 256, flagp);
        else
            gemm_ln<0, 0><<<256, 256, 0, stream>>>(
                h, nullptr, nullptr, wscr + 262144, b2, (long)l * 256, xa,
                ln2s, ln2b, xa, (long)l * 256, flagp);
    }
}

// Round 12
// 322.445 us; speedup vs baseline: 1.0515x; 1.0515x over previous
//
#include <hip/hip_runtime.h>
#include <hip/hip_bf16.h>

#define CL 2
#define CB 4
#define CT 1024
#define CD 256
#define CH 4
#define CM 1024
#define CHD (CH * CD)      // 1024
#define NROW (CB * CT)     // 4096

typedef unsigned short ushort_t;
typedef __attribute__((ext_vector_type(8))) short short8v;   // 8 bf16 (4 VGPR)
typedef __attribute__((ext_vector_type(4))) float float4v;   // MFMA C/D frag

#define LOG2E 1.44269504088896f

__device__ __forceinline__ float bf2f(unsigned short u) {
    return __uint_as_float(((unsigned int)u) << 16);
}
__device__ __forceinline__ unsigned short f2bf(float f) {
    unsigned int x = __float_as_uint(f);
    return (unsigned short)((x + 0x7fffu + ((x >> 16) & 1u)) >> 16);
}

// ---------------------------------------------------------------------------
// Input-dtype detection (2048 elems; fp32-underlying -> ~430 anomalies, bf16 0)
// ---------------------------------------------------------------------------
__global__ __launch_bounds__(256) void detect_kernel(
    const ushort_t* __restrict__ w, int n, int* __restrict__ flag)
{
    __shared__ int red[256];
    int c = 0;
    for (int i = threadIdx.x; i < n; i += 256) {
        float v = bf2f(w[i]);
        if (!(fabsf(v) <= 1e6f)) c++;
    }
    red[threadIdx.x] = c;
    __syncthreads();
    for (int s = 128; s > 0; s >>= 1) {
        if (threadIdx.x < s) red[threadIdx.x] += red[threadIdx.x + s];
        __syncthreads();
    }
    if (threadIdx.x == 0) flag[0] = (red[0] < 8) ? 1 : 0;
}

// ---------------------------------------------------------------------------
// Prepass transpose: Wq/Wk/Wv/W1 (all [L][256][1024]) -> bf16 transposed.
// Grid (32, 8, 8): z = which*2 + l.
// ---------------------------------------------------------------------------
__global__ __launch_bounds__(256) void tconv_all(
    const void* __restrict__ Wq, const void* __restrict__ Wk,
    const void* __restrict__ Wv, const void* __restrict__ W1,
    ushort_t* __restrict__ wqkvT, ushort_t* __restrict__ w1T,
    const int* __restrict__ flagp)
{
    const int fbf = *flagp;
    const int z = blockIdx.z;
    const int which = z >> 1, l = z & 1;
    const void* in = (which == 0) ? Wq : (which == 1) ? Wk
                   : (which == 2) ? Wv : W1;
    ushort_t* out = (which < 3)
        ? wqkvT + (long)l * 3072 * 256 + (long)which * 1024 * 256
        : w1T + (long)l * 1024 * 256;
    const long zi = (long)l * 262144;

    __shared__ float tile[32][33];
    const int r0 = blockIdx.y * 32;
    const int c0 = blockIdx.x * 32;
    const int tx = threadIdx.x & 31;
    const int ty = threadIdx.x >> 5;
#pragma unroll
    for (int i = 0; i < 32; i += 8) {
        const long idx = zi + (long)(r0 + ty + i) * 1024 + c0 + tx;
        tile[ty + i][tx] = fbf ? bf2f(((const ushort_t*)in)[idx])
                               : ((const float*)in)[idx];
    }
    __syncthreads();
#pragma unroll
    for (int i = 0; i < 32; i += 8)
        out[(long)(c0 + ty + i) * 256 + r0 + tx] = f2bf(tile[tx][ty + i]);
}

// ---------------------------------------------------------------------------
// In-loop transpose: Wo & W2 (both [L][1024][256]) -> wscr[z][256][1024].
// ---------------------------------------------------------------------------
__global__ __launch_bounds__(256) void tconv2(
    const void* __restrict__ Wo, const void* __restrict__ W2,
    ushort_t* __restrict__ wscr, long ioff, const int* __restrict__ flagp)
{
    const int fbf = *flagp;
    const int z = blockIdx.z;
    const void* in = z ? W2 : Wo;
    ushort_t* out = wscr + (long)z * 262144;

    __shared__ float tile[32][33];
    const int r0 = blockIdx.y * 32;
    const int c0 = blockIdx.x * 32;
    const int tx = threadIdx.x & 31;
    const int ty = threadIdx.x >> 5;
#pragma unroll
    for (int i = 0; i < 32; i += 8) {
        const long idx = ioff + (long)(r0 + ty + i) * 256 + c0 + tx;
        tile[ty + i][tx] = fbf ? bf2f(((const ushort_t*)in)[idx])
                               : ((const float*)in)[idx];
    }
    __syncthreads();
#pragma unroll
    for (int i = 0; i < 32; i += 8)
        out[(long)(c0 + ty + i) * 1024 + r0 + tx] = f2bf(tile[tx][ty + i]);
}

// ---------------------------------------------------------------------------
// QKV projection (merged, verified r7-r11; padded LDS stride 40).
// ---------------------------------------------------------------------------
__global__ __launch_bounds__(256) void qkv_proj(
    const ushort_t* __restrict__ A, const ushort_t* __restrict__ B,
    const void* __restrict__ bq, const void* __restrict__ bk,
    const void* __restrict__ bv, ushort_t* __restrict__ qk,
    ushort_t* __restrict__ vT, long boff, const int* __restrict__ flagp)
{
    const long m0 = (long)blockIdx.y * 128;
    const long n0 = (long)blockIdx.x * 128;

    __shared__ __align__(16) ushort_t As[128 * 40];
    __shared__ __align__(16) ushort_t Bs[128 * 40];

    const int tid = threadIdx.x;
    const int wave = tid >> 6;
    const int lane = tid & 63;
    const int quad = lane >> 4;
    const int lrow = lane & 15;
    const int wm = (wave >> 1) * 64;
    const int wn = (wave & 1) * 64;

    float4v acc[4][4];
#pragma unroll
    for (int i = 0; i < 4; ++i)
#pragma unroll
        for (int j = 0; j < 4; ++j)
            acc[i][j] = (float4v){0.f, 0.f, 0.f, 0.f};

    for (int k0 = 0; k0 < 256; k0 += 32) {
        __syncthreads();
#pragma unroll
        for (int p = 0; p < 2; ++p) {
            const int c = p * 256 + tid;
            const int row = c >> 2;
            const int kk = (c & 3) << 3;
            *reinterpret_cast<short8v*>(&As[row * 40 + kk]) =
                *reinterpret_cast<const short8v*>(&A[(m0 + row) * 256 + k0 + kk]);
            *reinterpret_cast<short8v*>(&Bs[row * 40 + kk]) =
                *reinterpret_cast<const short8v*>(&B[(n0 + row) * 256 + k0 + kk]);
        }
        __syncthreads();

        short8v af[4], bfv[4];
#pragma unroll
        for (int i = 0; i < 4; ++i) {
            af[i]  = *reinterpret_cast<const short8v*>(&As[(wm + i * 16 + lrow) * 40 + quad * 8]);
            bfv[i] = *reinterpret_cast<const short8v*>(&Bs[(wn + i * 16 + lrow) * 40 + quad * 8]);
        }
#pragma unroll
        for (int mi = 0; mi < 4; ++mi)
#pragma unroll
            for (int ni = 0; ni < 4; ++ni)
                acc[mi][ni] = __builtin_amdgcn_mfma_f32_16x16x32_bf16(
                    af[mi], bfv[ni], acc[mi][ni], 0, 0, 0);
    }

    const int fbf = *flagp;
#pragma unroll
    for (int mi = 0; mi < 4; ++mi) {
#pragma unroll
        for (int ni = 0; ni < 4; ++ni) {
            const long col = n0 + wn + ni * 16 + lrow;
            const long row0 = m0 + wm + mi * 16 + quad * 4;
            const void* bp;
            long bn;
            if (col < 1024)      { bp = bq; bn = col; }
            else if (col < 2048) { bp = bk; bn = col - 1024; }
            else                 { bp = bv; bn = col - 2048; }
            const float bias = fbf ? bf2f(((const ushort_t*)bp)[boff + bn])
                                   : ((const float*)bp)[boff + bn];
            if (col < 2048) {
#pragma unroll
                for (int r = 0; r < 4; ++r)
                    qk[(row0 + r) * 2048 + col] = f2bf(acc[mi][ni][r] + bias);
            } else {
                const long d = col - 2048;
                const long addr = ((row0 >> 10) << 2) * 262144 + d * 1024 + (row0 & 1023);
                ushort4 u;
                u.x = f2bf(acc[mi][ni][0] + bias);
                u.y = f2bf(acc[mi][ni][1] + bias);
                u.z = f2bf(acc[mi][ni][2] + bias);
                u.w = f2bf(acc[mi][ni][3] + bias);
                *reinterpret_cast<ushort4*>(&vT[addr]) = u;
            }
        }
    }
}

// ---------------------------------------------------------------------------
// mgemm64s: 64x64-tile split-K GEMM -> fp32 partials (r10 structure, proven;
// r11's gemm_ln fusion replacement regressed 26 us at 1 block/CU — reverted).
// Padded LDS stride 40. Grid (N/64, M/64, 2) = 512 blocks.
// AMODE 0: plain bf16 A. AMODE 1: combined attention partials (exp2 domain).
// ---------------------------------------------------------------------------
template <int AMODE>
__global__ __launch_bounds__(256) void mgemm64s(
    const ushort_t* __restrict__ A, const ushort_t* __restrict__ Ap1,
    const float2* __restrict__ ml, const ushort_t* __restrict__ B,
    float* __restrict__ P, int K2, int lda, int ldb)
{
    const int z = blockIdx.z;
    const long m0 = (long)blockIdx.y * 64;
    const long n0 = (long)blockIdx.x * 64;
    const int k_beg = z * K2;

    __shared__ __align__(16) ushort_t As[64 * 40];
    __shared__ __align__(16) ushort_t Bs[64 * 40];

    const int tid = threadIdx.x;
    const int wave = tid >> 6;
    const int lane = tid & 63;
    const int quad = lane >> 4;
    const int lrow = lane & 15;
    const int wm = (wave >> 1) * 32;
    const int wn = (wave & 1) * 32;

    const int ar = tid >> 2;
    const int ak = (tid & 3) << 3;

    float4v acc[2][2];
#pragma unroll
    for (int i = 0; i < 2; ++i)
#pragma unroll
        for (int j = 0; j < 2; ++j)
            acc[i][j] = (float4v){0.f, 0.f, 0.f, 0.f};

    for (int k0 = k_beg; k0 < k_beg + K2; k0 += 32) {
        __syncthreads();
        if constexpr (AMODE == 0) {
            *reinterpret_cast<short8v*>(&As[ar * 40 + ak]) =
                *reinterpret_cast<const short8v*>(&A[(m0 + ar) * (long)lda + k0 + ak]);
        } else {
            const long m = m0 + ar;
            const int hh = (k0 + ak) >> 8;
            const int bh = ((int)(m >> 10) << 2) + hh;
            const int trow = (int)(m & 1023);
            const float2 v0 = ml[bh * 1024 + trow];
            const float2 v1 = ml[(16 + bh) * 1024 + trow];
            const float mm = fmaxf(v0.x, v1.x);
            const float a0 = exp2f(v0.x - mm);
            const float a1 = exp2f(v1.x - mm);
            const float inv = 1.0f / (v0.y * a0 + v1.y * a1);
            const ushort4 u0a = *reinterpret_cast<const ushort4*>(&A[m * 1024 + k0 + ak]);
            const ushort4 u0b = *reinterpret_cast<const ushort4*>(&A[m * 1024 + k0 + ak + 4]);
            const ushort4 u1a = *reinterpret_cast<const ushort4*>(&Ap1[m * 1024 + k0 + ak]);
            const ushort4 u1b = *reinterpret_cast<const ushort4*>(&Ap1[m * 1024 + k0 + ak + 4]);
            short8v t8;
            t8[0] = (short)f2bf((bf2f(u0a.x) * a0 + bf2f(u1a.x) * a1) * inv);
            t8[1] = (short)f2bf((bf2f(u0a.y) * a0 + bf2f(u1a.y) * a1) * inv);
            t8[2] = (short)f2bf((bf2f(u0a.z) * a0 + bf2f(u1a.z) * a1) * inv);
            t8[3] = (short)f2bf((bf2f(u0a.w) * a0 + bf2f(u1a.w) * a1) * inv);
            t8[4] = (short)f2bf((bf2f(u0b.x) * a0 + bf2f(u1b.x) * a1) * inv);
            t8[5] = (short)f2bf((bf2f(u0b.y) * a0 + bf2f(u1b.y) * a1) * inv);
            t8[6] = (short)f2bf((bf2f(u0b.z) * a0 + bf2f(u1b.z) * a1) * inv);
            t8[7] = (short)f2bf((bf2f(u0b.w) * a0 + bf2f(u1b.w) * a1) * inv);
            *reinterpret_cast<short8v*>(&As[ar * 40 + ak]) = t8;
        }
        *reinterpret_cast<short8v*>(&Bs[ar * 40 + ak]) =
            *reinterpret_cast<const short8v*>(&B[(n0 + ar) * (long)ldb + k0 + ak]);
        __syncthreads();

        short8v af[2], bfv[2];
#pragma unroll
        for (int i = 0; i < 2; ++i) {
            af[i]  = *reinterpret_cast<const short8v*>(&As[(wm + i * 16 + lrow) * 40 + quad * 8]);
            bfv[i] = *reinterpret_cast<const short8v*>(&Bs[(wn + i * 16 + lrow) * 40 + quad * 8]);
        }
#pragma unroll
        for (int mi = 0; mi < 2; ++mi)
#pragma unroll
            for (int ni = 0; ni < 2; ++ni)
                acc[mi][ni] = __builtin_amdgcn_mfma_f32_16x16x32_bf16(
                    af[mi], bfv[ni], acc[mi][ni], 0, 0, 0);
    }

    float* Pz = P + (long)z * NROW * CD;
#pragma unroll
    for (int mi = 0; mi < 2; ++mi)
#pragma unroll
        for (int ni = 0; ni < 2; ++ni) {
            const long col = n0 + wn + ni * 16 + lrow;
            const long row0 = m0 + wm + mi * 16 + quad * 4;
#pragma unroll
            for (int r = 0; r < 4; ++r)
                Pz[(row0 + r) * CD + col] = acc[mi][ni][r];
        }
}

// ---------------------------------------------------------------------------
// mgemm64b: 64x64-tile full-K GEMM (MLP1), bias+relu, bf16 out. Padded LDS.
// ---------------------------------------------------------------------------
template <int RELU>
__global__ __launch_bounds__(256) void mgemm64b(
    const ushort_t* __restrict__ A, const ushort_t* __restrict__ B,
    const void* __restrict__ bias, ushort_t* __restrict__ C,
    int K, int lda, int ldb, int ldc, long boff,
    const int* __restrict__ flagp)
{
    const long m0 = (long)blockIdx.y * 64;
    const long n0 = (long)blockIdx.x * 64;

    __shared__ __align__(16) ushort_t As[64 * 40];
    __shared__ __align__(16) ushort_t Bs[64 * 40];

    const int tid = threadIdx.x;
    const int wave = tid >> 6;
    const int lane = tid & 63;
    const int quad = lane >> 4;
    const int lrow = lane & 15;
    const int wm = (wave >> 1) * 32;
    const int wn = (wave & 1) * 32;

    const int ar = tid >> 2;
    const int ak = (tid & 3) << 3;

    float4v acc[2][2];
#pragma unroll
    for (int i = 0; i < 2; ++i)
#pragma unroll
        for (int j = 0; j < 2; ++j)
            acc[i][j] = (float4v){0.f, 0.f, 0.f, 0.f};

    for (int k0 = 0; k0 < K; k0 += 32) {
        __syncthreads();
        *reinterpret_cast<short8v*>(&As[ar * 40 + ak]) =
            *reinterpret_cast<const short8v*>(&A[(m0 + ar) * (long)lda + k0 + ak]);
        *reinterpret_cast<short8v*>(&Bs[ar * 40 + ak]) =
            *reinterpret_cast<const short8v*>(&B[(n0 + ar) * (long)ldb + k0 + ak]);
        __syncthreads();

        short8v af[2], bfv[2];
#pragma unroll
        for (int i = 0; i < 2; ++i) {
            af[i]  = *reinterpret_cast<const short8v*>(&As[(wm + i * 16 + lrow) * 40 + quad * 8]);
            bfv[i] = *reinterpret_cast<const short8v*>(&Bs[(wn + i * 16 + lrow) * 40 + quad * 8]);
        }
#pragma unroll
        for (int mi = 0; mi < 2; ++mi)
#pragma unroll
            for (int ni = 0; ni < 2; ++ni)
                acc[mi][ni] = __builtin_amdgcn_mfma_f32_16x16x32_bf16(
                    af[mi], bfv[ni], acc[mi][ni], 0, 0, 0);
    }

    const int fbf = *flagp;
#pragma unroll
    for (int mi = 0; mi < 2; ++mi)
#pragma unroll
        for (int ni = 0; ni < 2; ++ni) {
            const long col = n0 + wn + ni * 16 + lrow;
            const long row0 = m0 + wm + mi * 16 + quad * 4;
            const float bv = fbf ? bf2f(((const ushort_t*)bias)[boff + col])
                                 : ((const float*)bias)[boff + col];
#pragma unroll
            for (int r = 0; r < 4; ++r) {
                float v = acc[mi][ni][r] + bv;
                if (RELU) v = fmaxf(v, 0.f);
                C[(row0 + r) * (long)ldc + col] = f2bf(v);
            }
        }
}

// ---------------------------------------------------------------------------
// Flash attention v6 (r11, measured 47.5 us): 32-key tiles, K+V LDS,
// S^T softmax, LAZY rescale (ref update only when tile max exceeds by >1.0
// log2), packed Ps stores.
// ---------------------------------------------------------------------------
__global__ __launch_bounds__(256) void flash_attn(
    const ushort_t* __restrict__ qk, const ushort_t* __restrict__ vT,
    ushort_t* __restrict__ op0, ushort_t* __restrict__ op1,
    float2* __restrict__ ml)
{
    const int bx = blockIdx.x;
    const int bh = bx & 15;
    const int qt = (bx >> 4) & 15;
    const int ck = bx >> 8;
    const int b = bh >> 2, h = bh & 3;

    __shared__ __align__(16) ushort_t Ks[32 * 264];
    __shared__ __align__(16) ushort_t Vs[256 * 40];
    __shared__ __align__(16) ushort_t Ps[4][16 * 40];

    const int tid = threadIdx.x;
    const int wave = tid >> 6;
    const int lane = tid & 63;
    const int quad = lane >> 4;
    const int lrow = lane & 15;

    const long qrow0 = (long)b * CT + qt * 64;
    const int qcol = h * 256;
    const int kcol = 1024 + h * 256;
    const long vbase = (long)bh * 256 * 1024;
    const float SC = 0.0625f * LOG2E;

    short8v qf[8];
#pragma unroll
    for (int kk = 0; kk < 8; ++kk)
        qf[kk] = *reinterpret_cast<const short8v*>(
            &qk[(qrow0 + wave * 16 + lrow) * 2048 + qcol + kk * 32 + quad * 8]);

    float mrun = -1e30f, lrun = 0.f;
    float4v oacc[16];
#pragma unroll
    for (int i = 0; i < 16; ++i) oacc[i] = (float4v){0.f, 0.f, 0.f, 0.f};

    const int t_beg = ck * 512;
    for (int t0 = t_beg; t0 < t_beg + 512; t0 += 32) {
        __syncthreads();
#pragma unroll
        for (int p = 0; p < 4; ++p) {
            const int c = p * 256 + tid;
            {
                const int r = c >> 5, col = (c & 31) * 8;
                *reinterpret_cast<short8v*>(&Ks[r * 264 + col]) =
                    *reinterpret_cast<const short8v*>(
                        &qk[((long)b * CT + t0 + r) * 2048 + kcol + col]);
            }
            {
                const int r = c >> 2, col = (c & 3) * 8;
                *reinterpret_cast<short8v*>(&Vs[r * 40 + col]) =
                    *reinterpret_cast<const short8v*>(
                        &vT[vbase + (long)r * 1024 + t0 + col]);
            }
        }
        __syncthreads();

        float4v sacc[2];
        sacc[0] = (float4v){0.f, 0.f, 0.f, 0.f};
        sacc[1] = (float4v){0.f, 0.f, 0.f, 0.f};
#pragma unroll
        for (int kk = 0; kk < 8; ++kk) {
#pragma unroll
            for (int ni = 0; ni < 2; ++ni) {
                short8v bk = *reinterpret_cast<const short8v*>(
                    &Ks[(ni * 16 + lrow) * 264 + kk * 32 + quad * 8]);
                sacc[ni] = __builtin_amdgcn_mfma_f32_16x16x32_bf16(
                    bk, qf[kk], sacc[ni], 0, 0, 0);   // swapped -> S^T
            }
        }
#pragma unroll
        for (int ni = 0; ni < 2; ++ni)
#pragma unroll
            for (int r = 0; r < 4; ++r)
                sacc[ni][r] *= SC;

        float mx = fmaxf(fmaxf(fmaxf(sacc[0][0], sacc[0][1]),
                               fmaxf(sacc[0][2], sacc[0][3])),
                         fmaxf(fmaxf(sacc[1][0], sacc[1][1]),
                               fmaxf(sacc[1][2], sacc[1][3])));
        mx = fmaxf(mx, __shfl_xor(mx, 16));
        mx = fmaxf(mx, __shfl_xor(mx, 32));

        if (__ballot(mx > mrun + 1.0f) != 0ull) {
            const float mnew = fmaxf(mrun, mx);
            const float alpha = exp2f(mrun - mnew);
            mrun = mnew;
            lrun *= alpha;
            float a4[4];
#pragma unroll
            for (int r = 0; r < 4; ++r)
                a4[r] = __shfl(alpha, quad * 4 + r);
#pragma unroll
            for (int ni = 0; ni < 16; ++ni)
#pragma unroll
                for (int r = 0; r < 4; ++r)
                    oacc[ni][r] *= a4[r];
        }

        float s = 0.f;
#pragma unroll
        for (int ni = 0; ni < 2; ++ni) {
            ushort4 pu;
#pragma unroll
            for (int r = 0; r < 4; ++r) {
                const float pv = exp2f(sacc[ni][r] - mrun);
                s += pv;
                (&pu.x)[r] = f2bf(pv);
            }
            *reinterpret_cast<ushort4*>(
                &Ps[wave][lrow * 40 + ni * 16 + quad * 4]) = pu;
        }
        s += __shfl_xor(s, 16);
        s += __shfl_xor(s, 32);
        lrun += s;

        {
            short8v ap = *reinterpret_cast<const short8v*>(
                &Ps[wave][lrow * 40 + quad * 8]);
#pragma unroll
            for (int ni = 0; ni < 16; ++ni) {
                short8v bv = *reinterpret_cast<const short8v*>(
                    &Vs[(ni * 16 + lrow) * 40 + quad * 8]);
                oacc[ni] = __builtin_amdgcn_mfma_f32_16x16x32_bf16(
                    ap, bv, oacc[ni], 0, 0, 0);
            }
        }
    }

    if (quad == 0)
        ml[((ck << 4) + bh) * 1024 + qt * 64 + wave * 16 + lrow] =
            make_float2(mrun, lrun);

    ushort_t* op = ck ? op1 : op0;
#pragma unroll
    for (int ni = 0; ni < 16; ++ni)
#pragma unroll
        for (int r = 0; r < 4; ++r)
            op[(qrow0 + wave * 16 + quad * 4 + r) * 1024 + (h << 8) + ni * 16 + lrow]
                = f2bf(oacc[ni][r]);
}

// ---------------------------------------------------------------------------
// ln_p: x = P0[row]+P1[row] + gbias + res; y = LN(x)*s + b.
// FINAL=1 writes d_out in flag dtype.
// ---------------------------------------------------------------------------
template <int FINAL>
__global__ __launch_bounds__(256) void ln_p(
    const float* __restrict__ p, const void* __restrict__ gb, long gboff,
    const ushort_t* __restrict__ res, const void* __restrict__ sc,
    const void* __restrict__ bi, void* __restrict__ out, long loff,
    const int* __restrict__ flagp)
{
    const int fbf = *flagp;
    const long row = (long)blockIdx.x * CD;
    const int t = threadIdx.x;
    const float gbv = fbf ? bf2f(((const ushort_t*)gb)[gboff + t])
                          : ((const float*)gb)[gboff + t];
    const float x = p[row + t] + p[(long)NROW * CD + row + t] + gbv + bf2f(res[row + t]);

    __shared__ float r1[256];
    __shared__ float r2[256];
    r1[t] = x;
    r2[t] = x * x;
    __syncthreads();
    for (int s = 128; s > 0; s >>= 1) {
        if (t < s) { r1[t] += r1[t + s]; r2[t] += r2[t + s]; }
        __syncthreads();
    }
    const float mean = r1[0] * (1.0f / CD);
    const float var = r2[0] * (1.0f / CD) - mean * mean;
    const float rstd = rsqrtf(var + 1e-5f);
    const float s_v = fbf ? bf2f(((const ushort_t*)sc)[loff + t]) : ((const float*)sc)[loff + t];
    const float b_v = fbf ? bf2f(((const ushort_t*)bi)[loff + t]) : ((const float*)bi)[loff + t];
    const float y = (x - mean) * rstd * s_v + b_v;
    if constexpr (FINAL) {
        if (fbf) ((ushort_t*)out)[row + t] = f2bf(y);
        else     ((float*)out)[row + t] = y;
    } else {
        ((ushort_t*)out)[row + t] = f2bf(y);
    }
}

__global__ __launch_bounds__(256) void in_convert(
    const void* __restrict__ in, ushort_t* __restrict__ x,
    const int* __restrict__ flagp)
{
    const int fbf = *flagp;
    const long i = ((long)blockIdx.x * 256 + threadIdx.x) << 2;
    if (fbf) {
        *reinterpret_cast<ushort4*>(x + i) =
            *reinterpret_cast<const ushort4*>((const ushort_t*)in + i);
    } else {
        float4 f = *reinterpret_cast<const float4*>((const float*)in + i);
        ushort4 u;
        u.x = f2bf(f.x); u.y = f2bf(f.y); u.z = f2bf(f.z); u.w = f2bf(f.w);
        *reinterpret_cast<ushort4*>(x + i) = u;
    }
}

// ---------------------------------------------------------------------------
// Orchestration. ws = 47.25 MB + 256 B. Dispatches: 3 + 8/layer x 2 = 19.
// (r11 lesson: fusing GEMM+LN into 1-block/CU kernels costs more than the
// launch gaps it saves — keep split-K + ln_p.)
// ---------------------------------------------------------------------------
extern "C" void kernel_launch(void* const* d_in, const int* in_sizes, int n_in,
                              void* d_out, int out_size, void* d_ws, size_t ws_size,
                              hipStream_t stream)
{
    const void* queries = d_in[0];
    const void* Wq = d_in[1];  const void* bq = d_in[2];
    const void* Wk = d_in[3];  const void* bk = d_in[4];
    const void* Wv = d_in[5];  const void* bv = d_in[6];
    const void* Wo = d_in[7];  const void* bo = d_in[8];
    const void* ln1s = d_in[9];  const void* ln1b = d_in[10];
    const void* W1 = d_in[11]; const void* b1 = d_in[12];
    const void* W2 = d_in[13]; const void* b2 = d_in[14];
    const void* ln2s = d_in[15]; const void* ln2b = d_in[16];

    char* p = (char*)d_ws;
    int* flagp = (int*)p;             p += 256;
    ushort_t* wqkvT = (ushort_t*)p;   p += (long)CL * 3072 * 256 * 2;  // 3 MB
    ushort_t* w1T   = (ushort_t*)p;   p += (long)CL * 1024 * 256 * 2;  // 1 MB
    ushort_t* wscr  = (ushort_t*)p;   p += (long)2 * 256 * 1024 * 2;   // 1 MB
    ushort_t* xa    = (ushort_t*)p;   p += (long)NROW * CD * 2;        // 2 MB
    ushort_t* qk    = (ushort_t*)p;   p += (long)NROW * 2048 * 2;      // 16 MB
    ushort_t* vT    = (ushort_t*)p;   p += (long)16 * 256 * 1024 * 2;  // 8 MB
    ushort_t* op0   = (ushort_t*)p;   p += (long)NROW * 1024 * 2;      // 8 MB
    ushort_t* op1   = (ushort_t*)p;   p += (long)NROW * 1024 * 2;      // 8 MB
    float2*   ml    = (float2*)p;     p += (long)2 * 16 * 1024 * 8;    // 0.25 MB
    ushort_t* h     = vT;             // MLP hidden reuses vT
    float*    pgem  = (float*)qk;     // fp32 partials reuse qk (dead post-flash)

    detect_kernel<<<1, 256, 0, stream>>>((const ushort_t*)Wq, 2048, flagp);
    tconv_all<<<dim3(32, 8, 8), 256, 0, stream>>>(
        Wq, Wk, Wv, W1, wqkvT, w1T, flagp);
    in_convert<<<(NROW * CD) / 1024, 256, 0, stream>>>(queries, xa, flagp);

    for (int l = 0; l < CL; ++l) {
        // 1) merged QKV projection -> qk [4096,2048] + vT[bh][d][t]
        qkv_proj<<<dim3(24, 32, 1), 256, 0, stream>>>(
            xa, wqkvT + (long)l * 3072 * 256, bq, bk, bv, qk, vT,
            (long)l * 1024, flagp);
        // 2) Wo^T and W2^T in one dispatch -> wscr[0], wscr[1]
        tconv2<<<dim3(8, 32, 2), 256, 0, stream>>>(
            Wo, W2, wscr, (long)l * 1024 * 256, flagp);
        // 3) flash attention (512 blocks, lazy rescale)
        flash_attn<<<512, 256, 0, stream>>>(qk, vT, op0, op1, ml);
        // 4) O projection with fused partial-combine -> fp32 pgem
        mgemm64s<1><<<dim3(4, 64, 2), 256, 0, stream>>>(
            op0, op1, ml, wscr, pgem, 512, 1024, 1024);
        // 5) xa = LN(pgem0+pgem1 + bo + xa)
        ln_p<0><<<NROW, 256, 0, stream>>>(pgem, bo, (long)l * 256, xa,
                                          ln1s, ln1b, xa, (long)l * 256, flagp);
        // 6) h = relu(xa @ w1T^T + b1)
        mgemm64b<1><<<dim3(16, 64, 1), 256, 0, stream>>>(
            xa, w1T + (long)l * 1024 * 256, b1, h,
            256, 256, 256, 1024, (long)l * 1024, flagp);
        // 7) MLP2 -> fp32 pgem  (B = W2^T in wscr[1])
        mgemm64s<0><<<dim3(4, 64, 2), 256, 0, stream>>>(
            h, nullptr, nullptr, wscr + 262144, pgem, 512, 1024, 1024);
        // 8) LN(pgem0+pgem1 + b2 + xa): final layer writes d_out directly
        if (l == CL - 1)
            ln_p<1><<<NROW, 256, 0, stream>>>(pgem, b2, (long)l * 256, xa,
                                              ln2s, ln2b, d_out, (long)l * 256, flagp);
        else
            ln_p<0><<<NROW, 256, 0, stream>>>(pgem, b2, (long)l * 256, xa,
                                              ln2s, ln2b, xa, (long)l * 256, flagp);
    }
}

// Round 13
// 305.244 us; speedup vs baseline: 1.1108x; 1.0564x over previous
//
#include <hip/hip_runtime.h>
#include <hip/hip_bf16.h>

#define CL 2
#define CB 4
#define CT 1024
#define CD 256
#define CH 4
#define CM 1024
#define CHD (CH * CD)      // 1024
#define NROW (CB * CT)     // 4096

typedef unsigned short ushort_t;
typedef __attribute__((ext_vector_type(8))) short short8v;   // 8 bf16 (4 VGPR)
typedef __attribute__((ext_vector_type(4))) float float4v;   // MFMA C/D frag

#define LOG2E 1.44269504088896f

__device__ __forceinline__ float bf2f(unsigned short u) {
    return __uint_as_float(((unsigned int)u) << 16);
}
__device__ __forceinline__ unsigned short f2bf(float f) {
    unsigned int x = __float_as_uint(f);
    return (unsigned short)((x + 0x7fffu + ((x >> 16) & 1u)) >> 16);
}

// ---------------------------------------------------------------------------
// Input-dtype detection (2048 elems; fp32-underlying -> ~430 anomalies, bf16 0)
// ---------------------------------------------------------------------------
__global__ __launch_bounds__(256) void detect_kernel(
    const ushort_t* __restrict__ w, int n, int* __restrict__ flag)
{
    __shared__ int red[256];
    int c = 0;
    for (int i = threadIdx.x; i < n; i += 256) {
        float v = bf2f(w[i]);
        if (!(fabsf(v) <= 1e6f)) c++;
    }
    red[threadIdx.x] = c;
    __syncthreads();
    for (int s = 128; s > 0; s >>= 1) {
        if (threadIdx.x < s) red[threadIdx.x] += red[threadIdx.x + s];
        __syncthreads();
    }
    if (threadIdx.x == 0) flag[0] = (red[0] < 8) ? 1 : 0;
}

// ---------------------------------------------------------------------------
// Prepass transpose: Wq/Wk/Wv/W1 (all [L][256][1024]) -> bf16 transposed.
// Grid (32, 8, 8): z = which*2 + l.
// ---------------------------------------------------------------------------
__global__ __launch_bounds__(256) void tconv_all(
    const void* __restrict__ Wq, const void* __restrict__ Wk,
    const void* __restrict__ Wv, const void* __restrict__ W1,
    ushort_t* __restrict__ wqkvT, ushort_t* __restrict__ w1T,
    const int* __restrict__ flagp)
{
    const int fbf = *flagp;
    const int z = blockIdx.z;
    const int which = z >> 1, l = z & 1;
    const void* in = (which == 0) ? Wq : (which == 1) ? Wk
                   : (which == 2) ? Wv : W1;
    ushort_t* out = (which < 3)
        ? wqkvT + (long)l * 3072 * 256 + (long)which * 1024 * 256
        : w1T + (long)l * 1024 * 256;
    const long zi = (long)l * 262144;

    __shared__ float tile[32][33];
    const int r0 = blockIdx.y * 32;
    const int c0 = blockIdx.x * 32;
    const int tx = threadIdx.x & 31;
    const int ty = threadIdx.x >> 5;
#pragma unroll
    for (int i = 0; i < 32; i += 8) {
        const long idx = zi + (long)(r0 + ty + i) * 1024 + c0 + tx;
        tile[ty + i][tx] = fbf ? bf2f(((const ushort_t*)in)[idx])
                               : ((const float*)in)[idx];
    }
    __syncthreads();
#pragma unroll
    for (int i = 0; i < 32; i += 8)
        out[(long)(c0 + ty + i) * 256 + r0 + tx] = f2bf(tile[tx][ty + i]);
}

// ---------------------------------------------------------------------------
// Merged QKV projection + Wo/W2 transpose (one dispatch, r13: saves a launch
// gap per layer; the two parts touch disjoint data).
// Blocks 0..767: qkv 128x128 tiles (nt = bx%24, mt = bx/24).
//   cols<2048 -> qk row-major; cols>=2048 -> V transposed into vT[bh][d][t].
// Blocks 768..1279: tconv2 (Wo -> wscr[0], W2 -> wscr[1], [1024][256]->T).
// ---------------------------------------------------------------------------
__global__ __launch_bounds__(256) void qkv_tconv(
    const ushort_t* __restrict__ A, const ushort_t* __restrict__ B,
    const void* __restrict__ bq, const void* __restrict__ bk,
    const void* __restrict__ bv, ushort_t* __restrict__ qk,
    ushort_t* __restrict__ vT,
    const void* __restrict__ Wo, const void* __restrict__ W2,
    ushort_t* __restrict__ wscr,
    long boff, long ioff, const int* __restrict__ flagp)
{
    __shared__ __align__(16) ushort_t As[128 * 40];
    __shared__ __align__(16) ushort_t Bs[128 * 40];
    __shared__ float tile[32][33];

    const int fbf = *flagp;
    const int bx = blockIdx.x;
    const int tid = threadIdx.x;

    if (bx >= 768) {
        // ---- tconv2 part ----
        const int t = bx - 768;          // 0..511
        const int zx = t & 7;            // col-tile (256/32)
        const int zy = (t >> 3) & 31;    // row-tile (1024/32)
        const int zz = t >> 8;           // 0 = Wo, 1 = W2
        const void* in = zz ? W2 : Wo;
        ushort_t* out = wscr + (long)zz * 262144;
        const int r0 = zy * 32;
        const int c0 = zx * 32;
        const int tx = tid & 31;
        const int ty = tid >> 5;
#pragma unroll
        for (int i = 0; i < 32; i += 8) {
            const long idx = ioff + (long)(r0 + ty + i) * 256 + c0 + tx;
            tile[ty + i][tx] = fbf ? bf2f(((const ushort_t*)in)[idx])
                                   : ((const float*)in)[idx];
        }
        __syncthreads();
#pragma unroll
        for (int i = 0; i < 32; i += 8)
            out[(long)(c0 + ty + i) * 1024 + r0 + tx] = f2bf(tile[tx][ty + i]);
        return;
    }

    // ---- qkv part ----
    const int nt = bx % 24;
    const int mt = bx / 24;
    const long m0 = (long)mt * 128;
    const long n0 = (long)nt * 128;

    const int wave = tid >> 6;
    const int lane = tid & 63;
    const int quad = lane >> 4;
    const int lrow = lane & 15;
    const int wm = (wave >> 1) * 64;
    const int wn = (wave & 1) * 64;

    float4v acc[4][4];
#pragma unroll
    for (int i = 0; i < 4; ++i)
#pragma unroll
        for (int j = 0; j < 4; ++j)
            acc[i][j] = (float4v){0.f, 0.f, 0.f, 0.f};

    for (int k0 = 0; k0 < 256; k0 += 32) {
        __syncthreads();
#pragma unroll
        for (int p = 0; p < 2; ++p) {
            const int c = p * 256 + tid;
            const int row = c >> 2;
            const int kk = (c & 3) << 3;
            *reinterpret_cast<short8v*>(&As[row * 40 + kk]) =
                *reinterpret_cast<const short8v*>(&A[(m0 + row) * 256 + k0 + kk]);
            *reinterpret_cast<short8v*>(&Bs[row * 40 + kk]) =
                *reinterpret_cast<const short8v*>(&B[(n0 + row) * 256 + k0 + kk]);
        }
        __syncthreads();

        short8v af[4], bfv[4];
#pragma unroll
        for (int i = 0; i < 4; ++i) {
            af[i]  = *reinterpret_cast<const short8v*>(&As[(wm + i * 16 + lrow) * 40 + quad * 8]);
            bfv[i] = *reinterpret_cast<const short8v*>(&Bs[(wn + i * 16 + lrow) * 40 + quad * 8]);
        }
#pragma unroll
        for (int mi = 0; mi < 4; ++mi)
#pragma unroll
            for (int ni = 0; ni < 4; ++ni)
                acc[mi][ni] = __builtin_amdgcn_mfma_f32_16x16x32_bf16(
                    af[mi], bfv[ni], acc[mi][ni], 0, 0, 0);
    }

#pragma unroll
    for (int mi = 0; mi < 4; ++mi) {
#pragma unroll
        for (int ni = 0; ni < 4; ++ni) {
            const long col = n0 + wn + ni * 16 + lrow;
            const long row0 = m0 + wm + mi * 16 + quad * 4;
            const void* bp;
            long bn;
            if (col < 1024)      { bp = bq; bn = col; }
            else if (col < 2048) { bp = bk; bn = col - 1024; }
            else                 { bp = bv; bn = col - 2048; }
            const float bias = fbf ? bf2f(((const ushort_t*)bp)[boff + bn])
                                   : ((const float*)bp)[boff + bn];
            if (col < 2048) {
#pragma unroll
                for (int r = 0; r < 4; ++r)
                    qk[(row0 + r) * 2048 + col] = f2bf(acc[mi][ni][r] + bias);
            } else {
                const long d = col - 2048;
                const long addr = ((row0 >> 10) << 2) * 262144 + d * 1024 + (row0 & 1023);
                ushort4 u;
                u.x = f2bf(acc[mi][ni][0] + bias);
                u.y = f2bf(acc[mi][ni][1] + bias);
                u.z = f2bf(acc[mi][ni][2] + bias);
                u.w = f2bf(acc[mi][ni][3] + bias);
                *reinterpret_cast<ushort4*>(&vT[addr]) = u;
            }
        }
    }
}

// ---------------------------------------------------------------------------
// mgemm64s: 64x64-tile split-K GEMM -> fp32 partials. BK=64 (r13: 8 MFMA per
// barrier-pair vs 4 — the 4-MFMA shape measured 175 TF). Grid (N/64, M/64, 2).
// AMODE 1: attention-partial combine with scales HOISTED out of the k-loop
// (r12 recomputed 2 ml loads + 2 exp2 + rcp per thread per k-iter).
// ---------------------------------------------------------------------------
template <int AMODE>
__global__ __launch_bounds__(256) void mgemm64s(
    const ushort_t* __restrict__ A, const ushort_t* __restrict__ Ap1,
    const float2* __restrict__ ml, const ushort_t* __restrict__ B,
    float* __restrict__ P, int K2, int lda, int ldb)
{
    const int z = blockIdx.z;
    const long m0 = (long)blockIdx.y * 64;
    const long n0 = (long)blockIdx.x * 64;
    const int k_beg = z * K2;

    __shared__ __align__(16) ushort_t As[64 * 72];
    __shared__ __align__(16) ushort_t Bs[64 * 72];

    const int tid = threadIdx.x;
    const int wave = tid >> 6;
    const int lane = tid & 63;
    const int quad = lane >> 4;
    const int lrow = lane & 15;
    const int wm = (wave >> 1) * 32;
    const int wn = (wave & 1) * 32;

    const int ar = tid >> 2;          // 0..63
    const int ak = (tid & 3) << 3;    // 0,8,16,24

    // AMODE1: combine scales for this thread's A-row, for the 2 heads this
    // K-chunk covers. k-invariant -> compute once.
    float s0h[2] = {0.f, 0.f}, s1h[2] = {0.f, 0.f};
    if constexpr (AMODE == 1) {
        const long m = m0 + ar;
        const int bhbase = ((int)(m >> 10) << 2);
        const int trow = (int)(m & 1023);
        const int h0 = k_beg >> 8;
#pragma unroll
        for (int i = 0; i < 2; ++i) {
            const int bh = bhbase + h0 + i;
            const float2 v0 = ml[bh * 1024 + trow];
            const float2 v1 = ml[(16 + bh) * 1024 + trow];
            const float mm = fmaxf(v0.x, v1.x);
            const float a0 = exp2f(v0.x - mm);
            const float a1 = exp2f(v1.x - mm);
            const float inv = 1.0f / (v0.y * a0 + v1.y * a1);
            s0h[i] = a0 * inv;
            s1h[i] = a1 * inv;
        }
    }

    float4v acc[2][2];
#pragma unroll
    for (int i = 0; i < 2; ++i)
#pragma unroll
        for (int j = 0; j < 2; ++j)
            acc[i][j] = (float4v){0.f, 0.f, 0.f, 0.f};

    for (int k0 = k_beg; k0 < k_beg + K2; k0 += 64) {
        __syncthreads();
#pragma unroll
        for (int p = 0; p < 2; ++p) {
            const int kc = p * 32 + ak;
            if constexpr (AMODE == 0) {
                *reinterpret_cast<short8v*>(&As[ar * 72 + kc]) =
                    *reinterpret_cast<const short8v*>(&A[(m0 + ar) * (long)lda + k0 + kc]);
            } else {
                const long m = m0 + ar;
                const int hi = ((k0 + kc) >> 8) - (k_beg >> 8);   // 0 or 1
                const float s0 = s0h[hi], s1 = s1h[hi];
                const ushort4 u0a = *reinterpret_cast<const ushort4*>(&A[m * 1024 + k0 + kc]);
                const ushort4 u0b = *reinterpret_cast<const ushort4*>(&A[m * 1024 + k0 + kc + 4]);
                const ushort4 u1a = *reinterpret_cast<const ushort4*>(&Ap1[m * 1024 + k0 + kc]);
                const ushort4 u1b = *reinterpret_cast<const ushort4*>(&Ap1[m * 1024 + k0 + kc + 4]);
                short8v t8;
                t8[0] = (short)f2bf(bf2f(u0a.x) * s0 + bf2f(u1a.x) * s1);
                t8[1] = (short)f2bf(bf2f(u0a.y) * s0 + bf2f(u1a.y) * s1);
                t8[2] = (short)f2bf(bf2f(u0a.z) * s0 + bf2f(u1a.z) * s1);
                t8[3] = (short)f2bf(bf2f(u0a.w) * s0 + bf2f(u1a.w) * s1);
                t8[4] = (short)f2bf(bf2f(u0b.x) * s0 + bf2f(u1b.x) * s1);
                t8[5] = (short)f2bf(bf2f(u0b.y) * s0 + bf2f(u1b.y) * s1);
                t8[6] = (short)f2bf(bf2f(u0b.z) * s0 + bf2f(u1b.z) * s1);
                t8[7] = (short)f2bf(bf2f(u0b.w) * s0 + bf2f(u1b.w) * s1);
                *reinterpret_cast<short8v*>(&As[ar * 72 + kc]) = t8;
            }
            *reinterpret_cast<short8v*>(&Bs[ar * 72 + kc]) =
                *reinterpret_cast<const short8v*>(&B[(n0 + ar) * (long)ldb + k0 + kc]);
        }
        __syncthreads();

#pragma unroll
        for (int kk = 0; kk < 2; ++kk) {
            short8v af[2], bfv[2];
#pragma unroll
            for (int i = 0; i < 2; ++i) {
                af[i]  = *reinterpret_cast<const short8v*>(
                    &As[(wm + i * 16 + lrow) * 72 + kk * 32 + quad * 8]);
                bfv[i] = *reinterpret_cast<const short8v*>(
                    &Bs[(wn + i * 16 + lrow) * 72 + kk * 32 + quad * 8]);
            }
#pragma unroll
            for (int mi = 0; mi < 2; ++mi)
#pragma unroll
                for (int ni = 0; ni < 2; ++ni)
                    acc[mi][ni] = __builtin_amdgcn_mfma_f32_16x16x32_bf16(
                        af[mi], bfv[ni], acc[mi][ni], 0, 0, 0);
        }
    }

    float* Pz = P + (long)z * NROW * CD;
#pragma unroll
    for (int mi = 0; mi < 2; ++mi)
#pragma unroll
        for (int ni = 0; ni < 2; ++ni) {
            const long col = n0 + wn + ni * 16 + lrow;
            const long row0 = m0 + wm + mi * 16 + quad * 4;
#pragma unroll
            for (int r = 0; r < 4; ++r)
                Pz[(row0 + r) * CD + col] = acc[mi][ni][r];
        }
}

// ---------------------------------------------------------------------------
// mgemm64b: 64x64-tile full-K GEMM (MLP1), BK=64, bias+relu, bf16 out.
// ---------------------------------------------------------------------------
template <int RELU>
__global__ __launch_bounds__(256) void mgemm64b(
    const ushort_t* __restrict__ A, const ushort_t* __restrict__ B,
    const void* __restrict__ bias, ushort_t* __restrict__ C,
    int K, int lda, int ldb, int ldc, long boff,
    const int* __restrict__ flagp)
{
    const long m0 = (long)blockIdx.y * 64;
    const long n0 = (long)blockIdx.x * 64;

    __shared__ __align__(16) ushort_t As[64 * 72];
    __shared__ __align__(16) ushort_t Bs[64 * 72];

    const int tid = threadIdx.x;
    const int wave = tid >> 6;
    const int lane = tid & 63;
    const int quad = lane >> 4;
    const int lrow = lane & 15;
    const int wm = (wave >> 1) * 32;
    const int wn = (wave & 1) * 32;

    const int ar = tid >> 2;
    const int ak = (tid & 3) << 3;

    float4v acc[2][2];
#pragma unroll
    for (int i = 0; i < 2; ++i)
#pragma unroll
        for (int j = 0; j < 2; ++j)
            acc[i][j] = (float4v){0.f, 0.f, 0.f, 0.f};

    for (int k0 = 0; k0 < K; k0 += 64) {
        __syncthreads();
#pragma unroll
        for (int p = 0; p < 2; ++p) {
            const int kc = p * 32 + ak;
            *reinterpret_cast<short8v*>(&As[ar * 72 + kc]) =
                *reinterpret_cast<const short8v*>(&A[(m0 + ar) * (long)lda + k0 + kc]);
            *reinterpret_cast<short8v*>(&Bs[ar * 72 + kc]) =
                *reinterpret_cast<const short8v*>(&B[(n0 + ar) * (long)ldb + k0 + kc]);
        }
        __syncthreads();

#pragma unroll
        for (int kk = 0; kk < 2; ++kk) {
            short8v af[2], bfv[2];
#pragma unroll
            for (int i = 0; i < 2; ++i) {
                af[i]  = *reinterpret_cast<const short8v*>(
                    &As[(wm + i * 16 + lrow) * 72 + kk * 32 + quad * 8]);
                bfv[i] = *reinterpret_cast<const short8v*>(
                    &Bs[(wn + i * 16 + lrow) * 72 + kk * 32 + quad * 8]);
            }
#pragma unroll
            for (int mi = 0; mi < 2; ++mi)
#pragma unroll
                for (int ni = 0; ni < 2; ++ni)
                    acc[mi][ni] = __builtin_amdgcn_mfma_f32_16x16x32_bf16(
                        af[mi], bfv[ni], acc[mi][ni], 0, 0, 0);
        }
    }

    const int fbf = *flagp;
#pragma unroll
    for (int mi = 0; mi < 2; ++mi)
#pragma unroll
        for (int ni = 0; ni < 2; ++ni) {
            const long col = n0 + wn + ni * 16 + lrow;
            const long row0 = m0 + wm + mi * 16 + quad * 4;
            const float bv = fbf ? bf2f(((const ushort_t*)bias)[boff + col])
                                 : ((const float*)bias)[boff + col];
#pragma unroll
            for (int r = 0; r < 4; ++r) {
                float v = acc[mi][ni][r] + bv;
                if (RELU) v = fmaxf(v, 0.f);
                C[(row0 + r) * (long)ldc + col] = f2bf(v);
            }
        }
}

// ---------------------------------------------------------------------------
// Flash attention v6 (proven r11/r12, ~47.5-48 us): 32-key tiles, K+V LDS,
// S^T softmax, lazy rescale, packed Ps stores.
// ---------------------------------------------------------------------------
__global__ __launch_bounds__(256) void flash_attn(
    const ushort_t* __restrict__ qk, const ushort_t* __restrict__ vT,
    ushort_t* __restrict__ op0, ushort_t* __restrict__ op1,
    float2* __restrict__ ml)
{
    const int bx = blockIdx.x;
    const int bh = bx & 15;
    const int qt = (bx >> 4) & 15;
    const int ck = bx >> 8;
    const int b = bh >> 2, h = bh & 3;

    __shared__ __align__(16) ushort_t Ks[32 * 264];
    __shared__ __align__(16) ushort_t Vs[256 * 40];
    __shared__ __align__(16) ushort_t Ps[4][16 * 40];

    const int tid = threadIdx.x;
    const int wave = tid >> 6;
    const int lane = tid & 63;
    const int quad = lane >> 4;
    const int lrow = lane & 15;

    const long qrow0 = (long)b * CT + qt * 64;
    const int qcol = h * 256;
    const int kcol = 1024 + h * 256;
    const long vbase = (long)bh * 256 * 1024;
    const float SC = 0.0625f * LOG2E;

    short8v qf[8];
#pragma unroll
    for (int kk = 0; kk < 8; ++kk)
        qf[kk] = *reinterpret_cast<const short8v*>(
            &qk[(qrow0 + wave * 16 + lrow) * 2048 + qcol + kk * 32 + quad * 8]);

    float mrun = -1e30f, lrun = 0.f;
    float4v oacc[16];
#pragma unroll
    for (int i = 0; i < 16; ++i) oacc[i] = (float4v){0.f, 0.f, 0.f, 0.f};

    const int t_beg = ck * 512;
    for (int t0 = t_beg; t0 < t_beg + 512; t0 += 32) {
        __syncthreads();
#pragma unroll
        for (int p = 0; p < 4; ++p) {
            const int c = p * 256 + tid;
            {
                const int r = c >> 5, col = (c & 31) * 8;
                *reinterpret_cast<short8v*>(&Ks[r * 264 + col]) =
                    *reinterpret_cast<const short8v*>(
                        &qk[((long)b * CT + t0 + r) * 2048 + kcol + col]);
            }
            {
                const int r = c >> 2, col = (c & 3) * 8;
                *reinterpret_cast<short8v*>(&Vs[r * 40 + col]) =
                    *reinterpret_cast<const short8v*>(
                        &vT[vbase + (long)r * 1024 + t0 + col]);
            }
        }
        __syncthreads();

        float4v sacc[2];
        sacc[0] = (float4v){0.f, 0.f, 0.f, 0.f};
        sacc[1] = (float4v){0.f, 0.f, 0.f, 0.f};
#pragma unroll
        for (int kk = 0; kk < 8; ++kk) {
#pragma unroll
            for (int ni = 0; ni < 2; ++ni) {
                short8v bk = *reinterpret_cast<const short8v*>(
                    &Ks[(ni * 16 + lrow) * 264 + kk * 32 + quad * 8]);
                sacc[ni] = __builtin_amdgcn_mfma_f32_16x16x32_bf16(
                    bk, qf[kk], sacc[ni], 0, 0, 0);   // swapped -> S^T
            }
        }
#pragma unroll
        for (int ni = 0; ni < 2; ++ni)
#pragma unroll
            for (int r = 0; r < 4; ++r)
                sacc[ni][r] *= SC;

        float mx = fmaxf(fmaxf(fmaxf(sacc[0][0], sacc[0][1]),
                               fmaxf(sacc[0][2], sacc[0][3])),
                         fmaxf(fmaxf(sacc[1][0], sacc[1][1]),
                               fmaxf(sacc[1][2], sacc[1][3])));
        mx = fmaxf(mx, __shfl_xor(mx, 16));
        mx = fmaxf(mx, __shfl_xor(mx, 32));

        if (__ballot(mx > mrun + 1.0f) != 0ull) {
            const float mnew = fmaxf(mrun, mx);
            const float alpha = exp2f(mrun - mnew);
            mrun = mnew;
            lrun *= alpha;
            float a4[4];
#pragma unroll
            for (int r = 0; r < 4; ++r)
                a4[r] = __shfl(alpha, quad * 4 + r);
#pragma unroll
            for (int ni = 0; ni < 16; ++ni)
#pragma unroll
                for (int r = 0; r < 4; ++r)
                    oacc[ni][r] *= a4[r];
        }

        float s = 0.f;
#pragma unroll
        for (int ni = 0; ni < 2; ++ni) {
            ushort4 pu;
#pragma unroll
            for (int r = 0; r < 4; ++r) {
                const float pv = exp2f(sacc[ni][r] - mrun);
                s += pv;
                (&pu.x)[r] = f2bf(pv);
            }
            *reinterpret_cast<ushort4*>(
                &Ps[wave][lrow * 40 + ni * 16 + quad * 4]) = pu;
        }
        s += __shfl_xor(s, 16);
        s += __shfl_xor(s, 32);
        lrun += s;

        {
            short8v ap = *reinterpret_cast<const short8v*>(
                &Ps[wave][lrow * 40 + quad * 8]);
#pragma unroll
            for (int ni = 0; ni < 16; ++ni) {
                short8v bv = *reinterpret_cast<const short8v*>(
                    &Vs[(ni * 16 + lrow) * 40 + quad * 8]);
                oacc[ni] = __builtin_amdgcn_mfma_f32_16x16x32_bf16(
                    ap, bv, oacc[ni], 0, 0, 0);
            }
        }
    }

    if (quad == 0)
        ml[((ck << 4) + bh) * 1024 + qt * 64 + wave * 16 + lrow] =
            make_float2(mrun, lrun);

    ushort_t* op = ck ? op1 : op0;
#pragma unroll
    for (int ni = 0; ni < 16; ++ni)
#pragma unroll
        for (int r = 0; r < 4; ++r)
            op[(qrow0 + wave * 16 + quad * 4 + r) * 1024 + (h << 8) + ni * 16 + lrow]
                = f2bf(oacc[ni][r]);
}

// ---------------------------------------------------------------------------
// ln_p: x = P0[row]+P1[row] + gbias + res; y = LN(x)*s + b.
// FINAL=1 writes d_out in flag dtype.
// ---------------------------------------------------------------------------
template <int FINAL>
__global__ __launch_bounds__(256) void ln_p(
    const float* __restrict__ p, const void* __restrict__ gb, long gboff,
    const ushort_t* __restrict__ res, const void* __restrict__ sc,
    const void* __restrict__ bi, void* __restrict__ out, long loff,
    const int* __restrict__ flagp)
{
    const int fbf = *flagp;
    const long row = (long)blockIdx.x * CD;
    const int t = threadIdx.x;
    const float gbv = fbf ? bf2f(((const ushort_t*)gb)[gboff + t])
                          : ((const float*)gb)[gboff + t];
    const float x = p[row + t] + p[(long)NROW * CD + row + t] + gbv + bf2f(res[row + t]);

    __shared__ float r1[256];
    __shared__ float r2[256];
    r1[t] = x;
    r2[t] = x * x;
    __syncthreads();
    for (int s = 128; s > 0; s >>= 1) {
        if (t < s) { r1[t] += r1[t + s]; r2[t] += r2[t + s]; }
        __syncthreads();
    }
    const float mean = r1[0] * (1.0f / CD);
    const float var = r2[0] * (1.0f / CD) - mean * mean;
    const float rstd = rsqrtf(var + 1e-5f);
    const float s_v = fbf ? bf2f(((const ushort_t*)sc)[loff + t]) : ((const float*)sc)[loff + t];
    const float b_v = fbf ? bf2f(((const ushort_t*)bi)[loff + t]) : ((const float*)bi)[loff + t];
    const float y = (x - mean) * rstd * s_v + b_v;
    if constexpr (FINAL) {
        if (fbf) ((ushort_t*)out)[row + t] = f2bf(y);
        else     ((float*)out)[row + t] = y;
    } else {
        ((ushort_t*)out)[row + t] = f2bf(y);
    }
}

__global__ __launch_bounds__(256) void in_convert(
    const void* __restrict__ in, ushort_t* __restrict__ x,
    const int* __restrict__ flagp)
{
    const int fbf = *flagp;
    const long i = ((long)blockIdx.x * 256 + threadIdx.x) << 2;
    if (fbf) {
        *reinterpret_cast<ushort4*>(x + i) =
            *reinterpret_cast<const ushort4*>((const ushort_t*)in + i);
    } else {
        float4 f = *reinterpret_cast<const float4*>((const float*)in + i);
        ushort4 u;
        u.x = f2bf(f.x); u.y = f2bf(f.y); u.z = f2bf(f.z); u.w = f2bf(f.w);
        *reinterpret_cast<ushort4*>(x + i) = u;
    }
}

// ---------------------------------------------------------------------------
// Orchestration. ws = 47.25 MB + 256 B. Dispatches: 3 + 7/layer x 2 = 17.
// ---------------------------------------------------------------------------
extern "C" void kernel_launch(void* const* d_in, const int* in_sizes, int n_in,
                              void* d_out, int out_size, void* d_ws, size_t ws_size,
                              hipStream_t stream)
{
    const void* queries = d_in[0];
    const void* Wq = d_in[1];  const void* bq = d_in[2];
    const void* Wk = d_in[3];  const void* bk = d_in[4];
    const void* Wv = d_in[5];  const void* bv = d_in[6];
    const void* Wo = d_in[7];  const void* bo = d_in[8];
    const void* ln1s = d_in[9];  const void* ln1b = d_in[10];
    const void* W1 = d_in[11]; const void* b1 = d_in[12];
    const void* W2 = d_in[13]; const void* b2 = d_in[14];
    const void* ln2s = d_in[15]; const void* ln2b = d_in[16];

    char* p = (char*)d_ws;
    int* flagp = (int*)p;             p += 256;
    ushort_t* wqkvT = (ushort_t*)p;   p += (long)CL * 3072 * 256 * 2;  // 3 MB
    ushort_t* w1T   = (ushort_t*)p;   p += (long)CL * 1024 * 256 * 2;  // 1 MB
    ushort_t* wscr  = (ushort_t*)p;   p += (long)2 * 256 * 1024 * 2;   // 1 MB
    ushort_t* xa    = (ushort_t*)p;   p += (long)NROW * CD * 2;        // 2 MB
    ushort_t* qk    = (ushort_t*)p;   p += (long)NROW * 2048 * 2;      // 16 MB
    ushort_t* vT    = (ushort_t*)p;   p += (long)16 * 256 * 1024 * 2;  // 8 MB
    ushort_t* op0   = (ushort_t*)p;   p += (long)NROW * 1024 * 2;      // 8 MB
    ushort_t* op1   = (ushort_t*)p;   p += (long)NROW * 1024 * 2;      // 8 MB
    float2*   ml    = (float2*)p;     p += (long)2 * 16 * 1024 * 8;    // 0.25 MB
    ushort_t* h     = vT;             // MLP hidden reuses vT
    float*    pgem  = (float*)qk;     // fp32 partials reuse qk (dead post-flash)

    detect_kernel<<<1, 256, 0, stream>>>((const ushort_t*)Wq, 2048, flagp);
    tconv_all<<<dim3(32, 8, 8), 256, 0, stream>>>(
        Wq, Wk, Wv, W1, wqkvT, w1T, flagp);
    in_convert<<<(NROW * CD) / 1024, 256, 0, stream>>>(queries, xa, flagp);

    for (int l = 0; l < CL; ++l) {
        // 1) merged QKV projection + Wo/W2 transpose (one dispatch)
        qkv_tconv<<<dim3(1280, 1, 1), 256, 0, stream>>>(
            xa, wqkvT + (long)l * 3072 * 256, bq, bk, bv, qk, vT,
            Wo, W2, wscr, (long)l * 1024, (long)l * 1024 * 256, flagp);
        // 2) flash attention (512 blocks, lazy rescale)
        flash_attn<<<512, 256, 0, stream>>>(qk, vT, op0, op1, ml);
        // 3) O projection with fused partial-combine (BK=64, hoisted scales)
        mgemm64s<1><<<dim3(4, 64, 2), 256, 0, stream>>>(
            op0, op1, ml, wscr, pgem, 512, 1024, 1024);
        // 4) xa = LN(pgem0+pgem1 + bo + xa)
        ln_p<0><<<NROW, 256, 0, stream>>>(pgem, bo, (long)l * 256, xa,
                                          ln1s, ln1b, xa, (long)l * 256, flagp);
        // 5) h = relu(xa @ w1T^T + b1)  (BK=64)
        mgemm64b<1><<<dim3(16, 64, 1), 256, 0, stream>>>(
            xa, w1T + (long)l * 1024 * 256, b1, h,
            256, 256, 256, 1024, (long)l * 1024, flagp);
        // 6) MLP2 -> fp32 pgem  (BK=64)
        mgemm64s<0><<<dim3(4, 64, 2), 256, 0, stream>>>(
            h, nullptr, nullptr, wscr + 262144, pgem, 512, 1024, 1024);
        // 7) LN(pgem0+pgem1 + b2 + xa): final layer writes d_out directly
        if (l == CL - 1)
            ln_p<1><<<NROW, 256, 0, stream>>>(pgem, b2, (long)l * 256, xa,
                                              ln2s, ln2b, d_out, (long)l * 256, flagp);
        else
            ln_p<0><<<NROW, 256, 0, stream>>>(pgem, b2, (long)l * 256, xa,
                                              ln2s, ln2b, xa, (long)l * 256, flagp);
    }
}